// Round 1
// baseline (2522.194 us; speedup 1.0000x reference)
//
#include <hip/hip_runtime.h>

#define NXN 96            // nodes per side
#define NNODE (NXN*NXN)   // 9216
#define NCW 95            // cells per side
#define NTHREADS 1024
#define MAXIT 4000

__device__ __forceinline__ double warp_red(double v){
  #pragma unroll
  for (int off = 32; off > 0; off >>= 1) v += __shfl_down(v, off, 64);
  return v;
}

__device__ double block_red(double v, double* s_red){
  const int tid = threadIdx.x, lane = tid & 63, wid = tid >> 6;
  v = warp_red(v);
  if (lane == 0) s_red[wid] = v;
  __syncthreads();
  if (wid == 0){
    double t = (lane < (NTHREADS/64)) ? s_red[lane] : 0.0;
    t = warp_red(t);
    if (lane == 0) s_red[0] = t;
  }
  __syncthreads();
  double r = s_red[0];
  __syncthreads();
  return r;
}

__global__ __launch_bounds__(NTHREADS, 1)
void fem_cg_kernel(const float* __restrict__ mask, float* __restrict__ out){
  __shared__ float  s_p[NNODE];
  __shared__ double s_red[NTHREADS/64];
  const int tid = threadIdx.x;
  const int bx = tid & 31, by = tid >> 5;    // 32x32 thread grid
  const int i0 = 3*bx, j0 = 3*by;            // each thread owns 3x3 nodes

  // Persistent sigma window: S[a][b] = sigma(cell i0-1+a, j0-1+b), 0 outside.
  float S[4][4];
  #pragma unroll
  for (int a = 0; a < 4; a++)
    #pragma unroll
    for (int b = 0; b < 4; b++){
      int ci = i0-1+a, cj = j0-1+b;
      float m = 0.f;
      if (ci >= 0 && ci < NCW && cj >= 0 && cj < NCW)
        m = 0.001f + 0.999f * mask[cj*NCW + ci];
      S[a][b] = m;
    }

  // Jacobi inverse-diagonal (0 on Dirichlet rows: i==0 or i==95)
  float invd[3][3];
  #pragma unroll
  for (int di = 0; di < 3; di++)
    #pragma unroll
    for (int dj = 0; dj < 3; dj++){
      float s00 = S[di+1][dj+1], sW = S[di][dj+1], sS = S[di+1][dj], sWS = S[di][dj];
      float cD = s00 + 3.f*sW + sS + sWS;
      bool isbc = (i0+di == 0) || (i0+di == NXN-1);
      invd[di][dj] = isbc ? 0.f : 1.f/cD;
    }

  // Warm start u0 = 1 - i/95 (exact BC). r0 = -(A u0) on free rows, computed
  // closed-form (u0 depends only on i; padded sigma zeroes off-grid coefs).
  float x[3][3], r[3][3], p[3][3], ap[3][3];
  double rzp = 0.0;
  #pragma unroll
  for (int di = 0; di < 3; di++)
    #pragma unroll
    for (int dj = 0; dj < 3; dj++){
      x[di][dj] = 0.f;
      int i = i0+di;
      float s00 = S[di+1][dj+1], sW = S[di][dj+1], sS = S[di+1][dj], sWS = S[di][dj];
      float uc = 1.f - (float)i     * (1.f/95.f);
      float uE = 1.f - (float)(i+1) * (1.f/95.f);
      float uW = 1.f - (float)(i-1) * (1.f/95.f);
      float v = (s00 + 3.f*sW + sS + sWS)*uc
              + 0.5f*(sS - s00)*uE
              + 0.5f*(sWS - sW)*uW
              - 0.5f*(s00 + 3.f*sW)*uc   // N neighbor: same i
              - 0.5f*(sS + 3.f*sWS)*uc   // S neighbor: same i
              - sW*uW                    // NW: i-1
              - sS*uE;                   // SE: i+1
      bool isbc = (i == 0) || (i == NXN-1);
      float rv = isbc ? 0.f : -v;
      r[di][dj] = rv;
      float z = rv * invd[di][dj];
      p[di][dj] = z;
      rzp += (double)rv * (double)z;
      s_p[(j0+dj)*NXN + i] = isbc ? 0.f : z;   // p0 (BC nodes stay 0 forever)
    }

  double rz  = block_red(rzp, s_red);   // barriers also publish s_p
  double tol = rz * 1e-11;

  if (rz > 0.0){
    for (int it = 0; it < MAXIT; ++it){
      // ---- Ap = A p : gather 5x5 window (9 own values from regs) ----
      float W[5][5];
      #pragma unroll
      for (int a = 0; a < 5; a++)
        #pragma unroll
        for (int b = 0; b < 5; b++){
          if (a >= 1 && a <= 3 && b >= 1 && b <= 3){ W[a][b] = p[a-1][b-1]; continue; }
          int gi = i0-1+a, gj = j0-1+b;
          W[a][b] = (gi >= 0 && gi < NXN && gj >= 0 && gj < NXN) ? s_p[gj*NXN + gi] : 0.f;
        }
      double papp = 0.0;
      #pragma unroll
      for (int di = 0; di < 3; di++)
        #pragma unroll
        for (int dj = 0; dj < 3; dj++){
          int i = i0+di;
          bool isbc = (i == 0) || (i == NXN-1);
          float s00 = S[di+1][dj+1], sW = S[di][dj+1], sS = S[di+1][dj], sWS = S[di][dj];
          float v = (s00 + 3.f*sW + sS + sWS)*W[di+1][dj+1]
                  + 0.5f*(sS - s00)*W[di+2][dj+1]
                  + 0.5f*(sWS - sW)*W[di][dj+1]
                  - 0.5f*(s00 + 3.f*sW)*W[di+1][dj+2]
                  - 0.5f*(sS + 3.f*sWS)*W[di+1][dj]
                  - sW*W[di][dj+2]
                  - sS*W[di+2][dj];
          v = isbc ? 0.f : v;
          ap[di][dj] = v;
          papp += (double)p[di][dj] * (double)v;
        }
      double pap = block_red(papp, s_red);
      if (!(pap > 0.0)) break;
      float alpha = (float)(rz / pap);

      double rznp = 0.0;
      #pragma unroll
      for (int di = 0; di < 3; di++)
        #pragma unroll
        for (int dj = 0; dj < 3; dj++){
          x[di][dj] += alpha * p[di][dj];
          float rn = r[di][dj] - alpha * ap[di][dj];
          r[di][dj] = rn;
          float z = rn * invd[di][dj];
          rznp += (double)rn * (double)z;
        }
      double rzn = block_red(rznp, s_red);
      if (rzn <= tol) break;
      float beta = (float)(rzn / rz);
      rz = rzn;
      #pragma unroll
      for (int di = 0; di < 3; di++)
        #pragma unroll
        for (int dj = 0; dj < 3; dj++){
          int i = i0+di;
          bool isbc = (i == 0) || (i == NXN-1);
          float pn = isbc ? 0.f : (r[di][dj]*invd[di][dj] + beta*p[di][dj]);
          p[di][dj] = pn;
          s_p[(j0+dj)*NXN + i] = pn;
        }
      __syncthreads();
    }
  }

  // ---- final u = u0 + x into s_p ----
  #pragma unroll
  for (int di = 0; di < 3; di++)
    #pragma unroll
    for (int dj = 0; dj < 3; dj++){
      int i = i0+di, j = j0+dj;
      float u;
      if (i == 0) u = 1.f;
      else if (i == NXN-1) u = 0.f;
      else u = 1.f - (float)i*(1.f/95.f) + x[di][dj];
      s_p[j*NXN + i] = u;
    }
  __syncthreads();

  // ---- energy: per cell sigma*0.5*(|gradA|^2 + |gradB|^2) ----
  float U[4][4];
  #pragma unroll
  for (int a = 0; a < 4; a++)
    #pragma unroll
    for (int b = 0; b < 4; b++){
      int gi = i0+a, gj = j0+b;
      U[a][b] = (gi < NXN && gj < NXN) ? s_p[gj*NXN + gi] : 0.f;
    }
  double ep = 0.0;
  #pragma unroll
  for (int di = 0; di < 3; di++)
    #pragma unroll
    for (int dj = 0; dj < 3; dj++){
      int ci = i0+di, cj = j0+dj;
      if (ci < NCW && cj < NCW){
        float sig = S[di+1][dj+1];
        float u00 = U[di][dj], uE = U[di+1][dj], uN = U[di][dj+1], uNE = U[di+1][dj+1];
        float gxA = uE - u00, gyA = uN - u00;
        float gxB = -2.f*uE + uNE + uN, gyB = uE - uNE;
        ep += (double)(sig * 0.5f * (gxA*gxA + gyA*gyA + gxB*gxB + gyB*gyB));
      }
    }
  double E = block_red(ep, s_red);
  if (tid == 0) out[0] = (float)E;
}

extern "C" void kernel_launch(void* const* d_in, const int* in_sizes, int n_in,
                              void* d_out, int out_size, void* d_ws, size_t ws_size,
                              hipStream_t stream){
  (void)d_ws; (void)ws_size; (void)out_size;
  // mask is the only 95*95=9025-element input (robust to input ordering)
  int mi = 0;
  for (int k = 0; k < n_in; k++) if (in_sizes[k] == 9025) { mi = k; break; }
  const float* mask = (const float*)d_in[mi];
  fem_cg_kernel<<<dim3(1), dim3(NTHREADS), 0, stream>>>(mask, (float*)d_out);
}

// Round 2
// 1672.967 us; speedup vs baseline: 1.5076x; 1.5076x over previous
//
#include <hip/hip_runtime.h>

#define NXN 96            // nodes per side
#define NNODE (NXN*NXN)   // 9216
#define NCW 95            // cells per side
#define NTHREADS 1024
#define NWAVES (NTHREADS/64)
#define MAXIT 4000
#define TOL_REL 1e-8

__device__ __forceinline__ double warp_red(double v){
  #pragma unroll
  for (int off = 32; off > 0; off >>= 1) v += __shfl_down(v, off, 64);
  return v;
}

__device__ __forceinline__ double sum16(const double* buf){
  double t = 0.0;
  #pragma unroll
  for (int k = 0; k < NWAVES; k++) t += buf[k];
  return t;
}

__global__ __launch_bounds__(NTHREADS, 1)
void fem_cg_kernel(const float* __restrict__ mask, float* __restrict__ out){
  __shared__ float  s_p[NNODE];
  __shared__ double s_redA[NWAVES];
  __shared__ double s_redB[NWAVES];
  const int tid = threadIdx.x, lane = tid & 63, wid = tid >> 6;
  const int bx = tid & 31, by = tid >> 5;    // 32x32 thread grid
  const int i0 = 3*bx, j0 = 3*by;            // each thread owns 3x3 nodes

  // Persistent sigma window: S[a][b] = sigma(cell i0-1+a, j0-1+b), 0 outside.
  float S[4][4];
  #pragma unroll
  for (int a = 0; a < 4; a++)
    #pragma unroll
    for (int b = 0; b < 4; b++){
      int ci = i0-1+a, cj = j0-1+b;
      float m = 0.f;
      if (ci >= 0 && ci < NCW && cj >= 0 && cj < NCW)
        m = 0.001f + 0.999f * mask[cj*NCW + ci];
      S[a][b] = m;
    }

  // Jacobi inverse-diagonal (0 on Dirichlet rows: i==0 or i==95)
  float invd[3][3];
  #pragma unroll
  for (int di = 0; di < 3; di++)
    #pragma unroll
    for (int dj = 0; dj < 3; dj++){
      float s00 = S[di+1][dj+1], sW = S[di][dj+1], sS = S[di+1][dj], sWS = S[di][dj];
      float cD = s00 + 3.f*sW + sS + sWS;
      bool isbc = (i0+di == 0) || (i0+di == NXN-1);
      invd[di][dj] = isbc ? 0.f : 1.f/cD;
    }

  // Warm start u0 = 1 - i/95 (exact BC). r0 = -(A u0) on free rows.
  float x[3][3], r[3][3], p[3][3], ap[3][3];
  double rzp = 0.0;
  #pragma unroll
  for (int di = 0; di < 3; di++)
    #pragma unroll
    for (int dj = 0; dj < 3; dj++){
      x[di][dj] = 0.f;
      int i = i0+di;
      float s00 = S[di+1][dj+1], sW = S[di][dj+1], sS = S[di+1][dj], sWS = S[di][dj];
      float uc = 1.f - (float)i     * (1.f/95.f);
      float uE = 1.f - (float)(i+1) * (1.f/95.f);
      float uW = 1.f - (float)(i-1) * (1.f/95.f);
      float v = (s00 + 3.f*sW + sS + sWS)*uc
              + 0.5f*(sS - s00)*uE
              + 0.5f*(sWS - sW)*uW
              - 0.5f*(s00 + 3.f*sW)*uc   // N neighbor: same i
              - 0.5f*(sS + 3.f*sWS)*uc   // S neighbor: same i
              - sW*uW                    // NW: i-1
              - sS*uE;                   // SE: i+1
      bool isbc = (i == 0) || (i == NXN-1);
      float rv = isbc ? 0.f : -v;
      r[di][dj] = rv;
      float z = rv * invd[di][dj];
      p[di][dj] = z;
      rzp += (double)rv * (double)z;
      s_p[(j0+dj)*NXN + i] = isbc ? 0.f : z;   // p0 (BC nodes stay 0 forever)
    }

  // init reduction: 1 barrier
  {
    double v = warp_red(rzp);
    if (lane == 0) s_redA[wid] = v;
  }
  __syncthreads();
  double rz  = sum16(s_redA);
  double tol = rz * TOL_REL;

  if (rz > 0.0){
    for (int it = 0; it < MAXIT; ++it){
      // ---- Ap = A p : gather 5x5 window (9 own values from regs) ----
      float W[5][5];
      #pragma unroll
      for (int a = 0; a < 5; a++)
        #pragma unroll
        for (int b = 0; b < 5; b++){
          if (a >= 1 && a <= 3 && b >= 1 && b <= 3){ W[a][b] = p[a-1][b-1]; continue; }
          int gi = i0-1+a, gj = j0-1+b;
          W[a][b] = (gi >= 0 && gi < NXN && gj >= 0 && gj < NXN) ? s_p[gj*NXN + gi] : 0.f;
        }
      double papp = 0.0;
      #pragma unroll
      for (int di = 0; di < 3; di++)
        #pragma unroll
        for (int dj = 0; dj < 3; dj++){
          int i = i0+di;
          bool isbc = (i == 0) || (i == NXN-1);
          float s00 = S[di+1][dj+1], sW = S[di][dj+1], sS = S[di+1][dj], sWS = S[di][dj];
          float v = (s00 + 3.f*sW + sS + sWS)*W[di+1][dj+1]
                  + 0.5f*(sS - s00)*W[di+2][dj+1]
                  + 0.5f*(sWS - sW)*W[di][dj+1]
                  - 0.5f*(s00 + 3.f*sW)*W[di+1][dj+2]
                  - 0.5f*(sS + 3.f*sWS)*W[di+1][dj]
                  - sW*W[di][dj+2]
                  - sS*W[di+2][dj];
          v = isbc ? 0.f : v;
          ap[di][dj] = v;
          papp += (double)p[di][dj] * (double)v;
        }
      // reduction 1 (pap): 1 barrier, buffer B
      {
        double v = warp_red(papp);
        if (lane == 0) s_redB[wid] = v;
      }
      __syncthreads();
      double pap = sum16(s_redB);
      if (!(pap > 0.0)) break;
      float alpha = (float)(rz / pap);

      double rznp = 0.0;
      #pragma unroll
      for (int di = 0; di < 3; di++)
        #pragma unroll
        for (int dj = 0; dj < 3; dj++){
          x[di][dj] += alpha * p[di][dj];
          float rn = r[di][dj] - alpha * ap[di][dj];
          r[di][dj] = rn;
          float z = rn * invd[di][dj];
          rznp += (double)rn * (double)z;
        }
      // reduction 2 (rzn): 1 barrier, buffer A
      {
        double v = warp_red(rznp);
        if (lane == 0) s_redA[wid] = v;
      }
      __syncthreads();
      double rzn = sum16(s_redA);
      if (rzn <= tol) break;
      float beta = (float)(rzn / rz);
      rz = rzn;
      #pragma unroll
      for (int di = 0; di < 3; di++)
        #pragma unroll
        for (int dj = 0; dj < 3; dj++){
          int i = i0+di;
          bool isbc = (i == 0) || (i == NXN-1);
          float pn = isbc ? 0.f : (r[di][dj]*invd[di][dj] + beta*p[di][dj]);
          p[di][dj] = pn;
          s_p[(j0+dj)*NXN + i] = pn;
        }
      __syncthreads();   // publish p: barrier 3
    }
  }

  // ---- final u = u0 + x into s_p ----
  // (safe: all loop exits have a barrier between the last s_p reads and here)
  #pragma unroll
  for (int di = 0; di < 3; di++)
    #pragma unroll
    for (int dj = 0; dj < 3; dj++){
      int i = i0+di, j = j0+dj;
      float u;
      if (i == 0) u = 1.f;
      else if (i == NXN-1) u = 0.f;
      else u = 1.f - (float)i*(1.f/95.f) + x[di][dj];
      s_p[j*NXN + i] = u;
    }
  __syncthreads();

  // ---- energy: per cell sigma*0.5*(|gradA|^2 + |gradB|^2) ----
  float U[4][4];
  #pragma unroll
  for (int a = 0; a < 4; a++)
    #pragma unroll
    for (int b = 0; b < 4; b++){
      int gi = i0+a, gj = j0+b;
      U[a][b] = (gi < NXN && gj < NXN) ? s_p[gj*NXN + gi] : 0.f;
    }
  double ep = 0.0;
  #pragma unroll
  for (int di = 0; di < 3; di++)
    #pragma unroll
    for (int dj = 0; dj < 3; dj++){
      int ci = i0+di, cj = j0+dj;
      if (ci < NCW && cj < NCW){
        float sig = S[di+1][dj+1];
        float u00 = U[di][dj], uE = U[di+1][dj], uN = U[di][dj+1], uNE = U[di+1][dj+1];
        float gxA = uE - u00, gyA = uN - u00;
        float gxB = -2.f*uE + uNE + uN, gyB = uE - uNE;
        ep += (double)(sig * 0.5f * (gxA*gxA + gyA*gyA + gxB*gxB + gyB*gyB));
      }
    }
  {
    double v = warp_red(ep);
    if (lane == 0) s_redB[wid] = v;
  }
  __syncthreads();
  if (tid == 0) out[0] = (float)sum16(s_redB);
}

extern "C" void kernel_launch(void* const* d_in, const int* in_sizes, int n_in,
                              void* d_out, int out_size, void* d_ws, size_t ws_size,
                              hipStream_t stream){
  (void)d_ws; (void)ws_size; (void)out_size;
  int mi = 0;
  for (int k = 0; k < n_in; k++) if (in_sizes[k] == 9025) { mi = k; break; }
  const float* mask = (const float*)d_in[mi];
  fem_cg_kernel<<<dim3(1), dim3(NTHREADS), 0, stream>>>(mask, (float*)d_out);
}

// Round 3
// 1066.104 us; speedup vs baseline: 2.3658x; 1.5692x over previous
//
#include <hip/hip_runtime.h>

#define NXN 96            // nodes per side
#define NNODE (NXN*NXN)   // 9216
#define NCW 95            // cells per side
#define NTHREADS 1024
#define NWAVES (NTHREADS/64)
#define MAXIT 4000
#define TOL_REL 1e-7

__device__ __forceinline__ void dual_warp_red(double& a, double& b){
  #pragma unroll
  for (int off = 32; off > 0; off >>= 1){
    a += __shfl_down(a, off, 64);   // two independent chains -> overlapped latency
    b += __shfl_down(b, off, 64);
  }
}

__device__ __forceinline__ double sum16(const double* buf){
  double t = 0.0;
  #pragma unroll
  for (int k = 0; k < NWAVES; k++) t += buf[k];
  return t;
}

__global__ __launch_bounds__(NTHREADS, 1)
void fem_cg_kernel(const float* __restrict__ mask, float* __restrict__ out){
  __shared__ float  s_z[NNODE];
  __shared__ double s_gA[NWAVES];
  __shared__ double s_gB[NWAVES];
  const int tid = threadIdx.x, lane = tid & 63, wid = tid >> 6;
  const int bx = tid & 31, by = tid >> 5;    // 32x32 thread grid
  const int i0 = 3*bx, j0 = 3*by;            // each thread owns 3x3 nodes

  // Persistent sigma window: S[a][b] = sigma(cell i0-1+a, j0-1+b), 0 outside.
  float S[4][4];
  #pragma unroll
  for (int a = 0; a < 4; a++)
    #pragma unroll
    for (int b = 0; b < 4; b++){
      int ci = i0-1+a, cj = j0-1+b;
      float m = 0.f;
      if (ci >= 0 && ci < NCW && cj >= 0 && cj < NCW)
        m = 0.001f + 0.999f * mask[cj*NCW + ci];
      S[a][b] = m;
    }

  // Jacobi inverse-diagonal (0 on Dirichlet rows: i==0 or i==95)
  float invd[3][3];
  #pragma unroll
  for (int di = 0; di < 3; di++)
    #pragma unroll
    for (int dj = 0; dj < 3; dj++){
      float s00 = S[di+1][dj+1], sW = S[di][dj+1], sS = S[di+1][dj], sWS = S[di][dj];
      float cD = s00 + 3.f*sW + sS + sWS;
      bool isbc = (i0+di == 0) || (i0+di == NXN-1);
      invd[di][dj] = isbc ? 0.f : 1.f/cD;
    }

  // Warm start u0 = 1 - i/95 (exact BC). r0 = -(A u0) on free rows.
  float x[3][3], r[3][3], z[3][3], p[3][3], s[3][3], w[3][3];
  #pragma unroll
  for (int di = 0; di < 3; di++)
    #pragma unroll
    for (int dj = 0; dj < 3; dj++){
      x[di][dj] = 0.f; p[di][dj] = 0.f; s[di][dj] = 0.f;
      int i = i0+di;
      float s00 = S[di+1][dj+1], sW = S[di][dj+1], sS = S[di+1][dj], sWS = S[di][dj];
      float uc = 1.f - (float)i     * (1.f/95.f);
      float uE = 1.f - (float)(i+1) * (1.f/95.f);
      float uW = 1.f - (float)(i-1) * (1.f/95.f);
      float v = (s00 + 3.f*sW + sS + sWS)*uc
              + 0.5f*(sS - s00)*uE
              + 0.5f*(sWS - sW)*uW
              - 0.5f*(s00 + 3.f*sW)*uc   // N neighbor: same i
              - 0.5f*(sS + 3.f*sWS)*uc   // S neighbor: same i
              - sW*uW                    // NW: i-1
              - sS*uE;                   // SE: i+1
      bool isbc = (i == 0) || (i == NXN-1);
      float rv = isbc ? 0.f : -v;
      r[di][dj] = rv;
      float zv = rv * invd[di][dj];
      z[di][dj] = zv;
      s_z[(j0+dj)*NXN + i] = zv;          // publish z0 (BC nodes stay 0 forever)
    }

  double gamma_old = 1.0, alpha_old = 1.0, tol = 0.0;

  // ---- Chronopoulos-Gear PCG: ONE reduction point, TWO barriers per iter ----
  for (int it = 0; it < MAXIT; ++it){
    __syncthreads();                       // publish of z visible

    // w = A z : gather 5x5 window (own 9 from registers)
    float W[5][5];
    #pragma unroll
    for (int a = 0; a < 5; a++)
      #pragma unroll
      for (int b = 0; b < 5; b++){
        if (a >= 1 && a <= 3 && b >= 1 && b <= 3){ W[a][b] = z[a-1][b-1]; continue; }
        int gi = i0-1+a, gj = j0-1+b;
        W[a][b] = (gi >= 0 && gi < NXN && gj >= 0 && gj < NXN) ? s_z[gj*NXN + gi] : 0.f;
      }
    double gp = 0.0, dp = 0.0;             // gamma = r.z, delta = w.z
    #pragma unroll
    for (int di = 0; di < 3; di++)
      #pragma unroll
      for (int dj = 0; dj < 3; dj++){
        int i = i0+di;
        bool isbc = (i == 0) || (i == NXN-1);
        float s00 = S[di+1][dj+1], sW = S[di][dj+1], sS = S[di+1][dj], sWS = S[di][dj];
        float v = (s00 + 3.f*sW + sS + sWS)*W[di+1][dj+1]
                + 0.5f*(sS - s00)*W[di+2][dj+1]
                + 0.5f*(sWS - sW)*W[di][dj+1]
                - 0.5f*(s00 + 3.f*sW)*W[di+1][dj+2]
                - 0.5f*(sS + 3.f*sWS)*W[di+1][dj]
                - sW*W[di][dj+2]
                - sS*W[di+2][dj];
        v = isbc ? 0.f : v;
        w[di][dj] = v;
        gp += (double)r[di][dj] * (double)z[di][dj];
        dp += (double)v * (double)z[di][dj];
      }
    dual_warp_red(gp, dp);
    if (lane == 0){ s_gA[wid] = gp; s_gB[wid] = dp; }
    __syncthreads();                       // reduction partials visible
    double gamma = sum16(s_gA);
    double delta = sum16(s_gB);

    if (it == 0) tol = gamma * TOL_REL;
    if (gamma <= tol || !(delta > 0.0)) break;

    double beta  = (it == 0) ? 0.0 : gamma / gamma_old;
    double alpha = (it == 0) ? gamma / delta
                             : gamma / (delta - beta * gamma / alpha_old);
    gamma_old = gamma; alpha_old = alpha;
    float bf = (float)beta, af = (float)alpha;

    #pragma unroll
    for (int di = 0; di < 3; di++)
      #pragma unroll
      for (int dj = 0; dj < 3; dj++){
        float pn = z[di][dj] + bf * p[di][dj];
        float sn = w[di][dj] + bf * s[di][dj];
        p[di][dj] = pn; s[di][dj] = sn;
        x[di][dj] += af * pn;
        float rn = r[di][dj] - af * sn;
        r[di][dj] = rn;
        float zn = rn * invd[di][dj];
        z[di][dj] = zn;
        s_z[(j0+dj)*NXN + (i0+di)] = zn;   // publish next z (BC rows write 0)
      }
    // next iteration's top barrier makes the publish visible
  }

  // ---- final u = u0 + x into s_z ----
  // (all loop exits passed the reduction barrier after the last s_z reads)
  #pragma unroll
  for (int di = 0; di < 3; di++)
    #pragma unroll
    for (int dj = 0; dj < 3; dj++){
      int i = i0+di, j = j0+dj;
      float u;
      if (i == 0) u = 1.f;
      else if (i == NXN-1) u = 0.f;
      else u = 1.f - (float)i*(1.f/95.f) + x[di][dj];
      s_z[j*NXN + i] = u;
    }
  __syncthreads();

  // ---- energy: per cell sigma*0.5*(|gradA|^2 + |gradB|^2) ----
  float U[4][4];
  #pragma unroll
  for (int a = 0; a < 4; a++)
    #pragma unroll
    for (int b = 0; b < 4; b++){
      int gi = i0+a, gj = j0+b;
      U[a][b] = (gi < NXN && gj < NXN) ? s_z[gj*NXN + gi] : 0.f;
    }
  double ep = 0.0;
  #pragma unroll
  for (int di = 0; di < 3; di++)
    #pragma unroll
    for (int dj = 0; dj < 3; dj++){
      int ci = i0+di, cj = j0+dj;
      if (ci < NCW && cj < NCW){
        float sig = S[di+1][dj+1];
        float u00 = U[di][dj], uE = U[di+1][dj], uN = U[di][dj+1], uNE = U[di+1][dj+1];
        float gxA = uE - u00, gyA = uN - u00;
        float gxB = -2.f*uE + uNE + uN, gyB = uE - uNE;
        ep += (double)(sig * 0.5f * (gxA*gxA + gyA*gyA + gxB*gxB + gyB*gyB));
      }
    }
  {
    double dummy = 0.0;
    dual_warp_red(ep, dummy);
    if (lane == 0) s_gA[wid] = ep;
  }
  __syncthreads();
  if (tid == 0) out[0] = (float)sum16(s_gA);
}

extern "C" void kernel_launch(void* const* d_in, const int* in_sizes, int n_in,
                              void* d_out, int out_size, void* d_ws, size_t ws_size,
                              hipStream_t stream){
  (void)d_ws; (void)ws_size; (void)out_size;
  int mi = 0;
  for (int k = 0; k < n_in; k++) if (in_sizes[k] == 9025) { mi = k; break; }
  const float* mask = (const float*)d_in[mi];
  fem_cg_kernel<<<dim3(1), dim3(NTHREADS), 0, stream>>>(mask, (float*)d_out);
}